// Round 1
// baseline (10272.485 us; speedup 1.0000x reference)
//
#include <hip/hip_runtime.h>
#include <math.h>

// Problem constants
#define VOCAB 10000
#define D 512
#define L 6
#define H 8
#define B 32
#define S 384
#define DK 64
#define DFF 2048
#define TOK (B * S)            // 12288 tokens
#define TD ((size_t)TOK * D)   // 6291456 floats per activation buffer

// Static workspace: x | h | q | k | v | extra  (ffn reuses q..extra = 4*TD)
__device__ float g_ws[6 * TD];

// ---------------------------------------------------------------------------
// Embedding + intensity projection: x[tok,d] = emb[id,d] + inten[tok]*iw[d] + ib[d]
__global__ __launch_bounds__(256) void embed_kernel(
    const int* __restrict__ ids, const float* __restrict__ inten,
    const float* __restrict__ emb, const float* __restrict__ iw,
    const float* __restrict__ ib, float* __restrict__ x) {
  int tok = blockIdx.x;
  int t = threadIdx.x;
  int id = ids[tok];
  float it = inten[tok];
  const float* er = emb + (size_t)id * D;
  float* xr = x + (size_t)tok * D;
  for (int d = t; d < D; d += 256)
    xr[d] = er[d] + it * iw[d] + ib[d];
}

// ---------------------------------------------------------------------------
// LayerNorm over D=512: one block (256 thr) per token
__global__ __launch_bounds__(256) void ln_kernel(
    const float* __restrict__ x, const float* __restrict__ w,
    const float* __restrict__ b, float* __restrict__ out) {
  int tok = blockIdx.x;
  int t = threadIdx.x;
  const float* xr = x + (size_t)tok * D;
  float v0 = xr[t], v1 = xr[t + 256];
  float s = v0 + v1;
  float ss = v0 * v0 + v1 * v1;
  #pragma unroll
  for (int off = 32; off >= 1; off >>= 1) {
    s += __shfl_down(s, off);
    ss += __shfl_down(ss, off);
  }
  __shared__ float sbuf[4], ssbuf[4];
  int wave = t >> 6, lane = t & 63;
  if (lane == 0) { sbuf[wave] = s; ssbuf[wave] = ss; }
  __syncthreads();
  s = sbuf[0] + sbuf[1] + sbuf[2] + sbuf[3];
  ss = ssbuf[0] + ssbuf[1] + ssbuf[2] + ssbuf[3];
  float mean = s * (1.0f / (float)D);
  float var = ss * (1.0f / (float)D) - mean * mean;
  float rstd = rsqrtf(var + 1e-5f);
  float* orow = out + (size_t)tok * D;
  orow[t]       = (v0 - mean) * rstd * w[t] + b[t];
  orow[t + 256] = (v1 - mean) * rstd * w[t + 256] + b[t + 256];
}

// ---------------------------------------------------------------------------
// Tiled fp32 GEMM: C[M,N] = A[M,K] @ Bw[K,N] (+bias, epilogue)
// MODE 0: C = acc + bias
// MODE 1: C = gelu_exact(acc + bias)
// MODE 2: C += acc + bias   (residual accumulate into existing C)
#define BM 64
#define BN 64
#define BKK 16
template <int MODE>
__global__ __launch_bounds__(256) void gemm_kernel(
    const float* __restrict__ A, const float* __restrict__ Bw,
    const float* __restrict__ bias, float* __restrict__ C,
    int M, int N, int K) {
  __shared__ float As[BKK][BM];
  __shared__ float Bs[BKK][BN];
  int t = threadIdx.x;
  int bm = blockIdx.y * BM;
  int bn = blockIdx.x * BN;
  int tx = t & 15, ty = t >> 4;
  int la_m = t >> 2;          // 0..63
  int la_k = (t & 3) * 4;     // 0,4,8,12
  int lb_k = t >> 4;          // 0..15
  int lb_n = (t & 15) * 4;    // 0..60
  float acc[4][4] = {};
  for (int k0 = 0; k0 < K; k0 += BKK) {
    float4 a4 = *(const float4*)(A + (size_t)(bm + la_m) * K + k0 + la_k);
    As[la_k + 0][la_m] = a4.x;
    As[la_k + 1][la_m] = a4.y;
    As[la_k + 2][la_m] = a4.z;
    As[la_k + 3][la_m] = a4.w;
    float4 b4 = *(const float4*)(Bw + (size_t)(k0 + lb_k) * N + bn + lb_n);
    *(float4*)&Bs[lb_k][lb_n] = b4;
    __syncthreads();
    #pragma unroll
    for (int kk = 0; kk < BKK; ++kk) {
      float av[4], bv[4];
      #pragma unroll
      for (int i = 0; i < 4; ++i) av[i] = As[kk][ty * 4 + i];
      #pragma unroll
      for (int j = 0; j < 4; ++j) bv[j] = Bs[kk][tx * 4 + j];
      #pragma unroll
      for (int i = 0; i < 4; ++i)
        #pragma unroll
        for (int j = 0; j < 4; ++j)
          acc[i][j] += av[i] * bv[j];
    }
    __syncthreads();
  }
  #pragma unroll
  for (int i = 0; i < 4; ++i) {
    int row = bm + ty * 4 + i;
    #pragma unroll
    for (int j = 0; j < 4; ++j) {
      int col = bn + tx * 4 + j;
      float v = acc[i][j] + bias[col];
      if (MODE == 1) v = 0.5f * v * (1.0f + erff(v * 0.70710678118654752f));
      size_t ci = (size_t)row * N + col;
      if (MODE == 2) v += C[ci];
      C[ci] = v;
    }
  }
}

// ---------------------------------------------------------------------------
// Flash-style attention: one block per (b*H+h, q_tile of 32 rows).
// q,k,v buffers are [TOK, D] with head h at cols h*64..h*64+63.
__global__ __launch_bounds__(256) void attn_kernel(
    const float* __restrict__ qg, const float* __restrict__ kg,
    const float* __restrict__ vg, const int* __restrict__ ids,
    float* __restrict__ out) {
  int bh = blockIdx.x;
  int b = bh >> 3, hh = bh & 7;
  int q0 = blockIdx.y * 32;
  int t = threadIdx.x;
  int r = t >> 3;   // query row within tile 0..31
  int g = t & 7;    // lane within row-group
  __shared__ float Qs[32][65];
  __shared__ float Ks[64][65];
  __shared__ float Vs[64][65];
  __shared__ float Ps[32][65];
  const size_t base = (size_t)b * S * D + (size_t)hh * DK;
  for (int idx = t; idx < 32 * 64; idx += 256) {
    int rr = idx >> 6, d = idx & 63;
    Qs[rr][d] = qg[base + (size_t)(q0 + rr) * D + d];
  }
  float acc[8] = {};
  float m = -INFINITY, l = 0.f;
  for (int kb = 0; kb < S; kb += 64) {
    __syncthreads();
    for (int idx = t; idx < 64 * 64; idx += 256) {
      int j = idx >> 6, d = idx & 63;
      Ks[j][d] = kg[base + (size_t)(kb + j) * D + d];
      Vs[j][d] = vg[base + (size_t)(kb + j) * D + d];
    }
    __syncthreads();
    float sc[8];
    float tmax = -INFINITY;
    #pragma unroll
    for (int jj = 0; jj < 8; ++jj) {
      int j = g + jj * 8;
      float sacc = 0.f;
      #pragma unroll
      for (int d = 0; d < 64; ++d) sacc += Qs[r][d] * Ks[j][d];
      sacc *= 0.125f;  // 1/sqrt(DK)
      if (ids[b * S + kb + j] == 0) sacc = -1e9f;
      sc[jj] = sacc;
      tmax = fmaxf(tmax, sacc);
    }
    #pragma unroll
    for (int off = 1; off < 8; off <<= 1)
      tmax = fmaxf(tmax, __shfl_xor(tmax, off));
    float newm = fmaxf(m, tmax);
    float scale = expf(m - newm);
    float psum = 0.f;
    #pragma unroll
    for (int jj = 0; jj < 8; ++jj) {
      float p = expf(sc[jj] - newm);
      Ps[r][g + jj * 8] = p;
      psum += p;
    }
    #pragma unroll
    for (int off = 1; off < 8; off <<= 1)
      psum += __shfl_xor(psum, off);
    l = l * scale + psum;
    #pragma unroll
    for (int i = 0; i < 8; ++i) acc[i] *= scale;
    m = newm;
    __syncthreads();  // make Ps visible (and ordered) before PV reads
    for (int j = 0; j < 64; ++j) {
      float p = Ps[r][j];
      #pragma unroll
      for (int i = 0; i < 8; ++i) acc[i] += p * Vs[j][g * 8 + i];
    }
  }
  float inv = 1.0f / l;
  float* orow = out + base + (size_t)(q0 + r) * D + g * 8;
  #pragma unroll
  for (int i = 0; i < 8; ++i) orow[i] = acc[i] * inv;
}

// ---------------------------------------------------------------------------
// Pool: out[b,d] = sum_s inten[b,s] * x[b,s,d]
__global__ __launch_bounds__(512) void pool_kernel(
    const float* __restrict__ x, const float* __restrict__ inten,
    float* __restrict__ out) {
  int b = blockIdx.x;
  int d = threadIdx.x;
  float acc = 0.f;
  for (int s = 0; s < S; ++s)
    acc += inten[b * S + s] * x[((size_t)b * S + s) * D + d];
  out[b * D + d] = acc;
}

// ---------------------------------------------------------------------------
extern "C" void kernel_launch(void* const* d_in, const int* in_sizes, int n_in,
                              void* d_out, int out_size, void* d_ws, size_t ws_size,
                              hipStream_t stream) {
  const int* input_id   = (const int*)d_in[0];
  const float* intensity = (const float*)d_in[1];
  const float* emb = (const float*)d_in[2];
  const float* iw  = (const float*)d_in[3];
  const float* ib  = (const float*)d_in[4];
  const float* Wq  = (const float*)d_in[5];
  const float* bq  = (const float*)d_in[6];
  const float* Wk  = (const float*)d_in[7];
  const float* bk  = (const float*)d_in[8];
  const float* Wv  = (const float*)d_in[9];
  const float* bv  = (const float*)d_in[10];
  const float* Wo  = (const float*)d_in[11];
  const float* bo  = (const float*)d_in[12];
  const float* ln1w = (const float*)d_in[13];
  const float* ln1b = (const float*)d_in[14];
  const float* ln2w = (const float*)d_in[15];
  const float* ln2b = (const float*)d_in[16];
  const float* W1  = (const float*)d_in[17];
  const float* b1  = (const float*)d_in[18];
  const float* W2  = (const float*)d_in[19];
  const float* b2  = (const float*)d_in[20];
  float* outp = (float*)d_out;

  void* wsptr = nullptr;
  hipGetSymbolAddress(&wsptr, HIP_SYMBOL(g_ws));
  float* x = (float*)wsptr;
  float* h = x + TD;
  float* q = x + 2 * TD;
  float* k = x + 3 * TD;
  float* v = x + 4 * TD;
  float* ffn = q;  // spans q..v+TD = 4*TD floats

  embed_kernel<<<TOK, 256, 0, stream>>>(input_id, intensity, emb, iw, ib, x);

  for (int l = 0; l < L; ++l) {
    const float* Wq_l = Wq + (size_t)l * D * D;
    const float* Wk_l = Wk + (size_t)l * D * D;
    const float* Wv_l = Wv + (size_t)l * D * D;
    const float* Wo_l = Wo + (size_t)l * D * D;
    const float* W1_l = W1 + (size_t)l * D * DFF;
    const float* W2_l = W2 + (size_t)l * DFF * D;
    const float* bq_l = bq + (size_t)l * D;
    const float* bk_l = bk + (size_t)l * D;
    const float* bv_l = bv + (size_t)l * D;
    const float* bo_l = bo + (size_t)l * D;
    const float* b1_l = b1 + (size_t)l * DFF;
    const float* b2_l = b2 + (size_t)l * D;

    // LN1
    ln_kernel<<<TOK, 256, 0, stream>>>(x, ln1w + (size_t)l * D, ln1b + (size_t)l * D, h);
    // QKV projections
    dim3 g512(D / BN, TOK / BM);
    gemm_kernel<0><<<g512, 256, 0, stream>>>(h, Wq_l, bq_l, q, TOK, D, D);
    gemm_kernel<0><<<g512, 256, 0, stream>>>(h, Wk_l, bk_l, k, TOK, D, D);
    gemm_kernel<0><<<g512, 256, 0, stream>>>(h, Wv_l, bv_l, v, TOK, D, D);
    // attention -> h
    dim3 ga(B * H, S / 32);
    attn_kernel<<<ga, 256, 0, stream>>>(q, k, v, input_id, h);
    // O-projection + residual into x
    gemm_kernel<2><<<g512, 256, 0, stream>>>(h, Wo_l, bo_l, x, TOK, D, D);
    // LN2
    ln_kernel<<<TOK, 256, 0, stream>>>(x, ln2w + (size_t)l * D, ln2b + (size_t)l * D, h);
    // FFN
    dim3 gff1(DFF / BN, TOK / BM);
    gemm_kernel<1><<<gff1, 256, 0, stream>>>(h, W1_l, b1_l, ffn, TOK, DFF, D);
    gemm_kernel<2><<<g512, 256, 0, stream>>>(ffn, W2_l, b2_l, x, TOK, D, DFF);
  }

  pool_kernel<<<B, D, 0, stream>>>(x, intensity, outp);
}

// Round 2
// 1853.408 us; speedup vs baseline: 5.5425x; 5.5425x over previous
//
#include <hip/hip_runtime.h>
#include <math.h>

// Problem constants
#define VOCAB 10000
#define D 512
#define L 6
#define H 8
#define B 32
#define S 384
#define DK 64
#define DFF 2048
#define TOK (B * S)            // 12288 tokens
#define TD ((size_t)TOK * D)   // 6291456 elements per activation buffer

typedef unsigned short u16;
using bf16x8 = __attribute__((ext_vector_type(8))) short;
using f32x4  = __attribute__((ext_vector_type(4))) float;
using u16x4  = __attribute__((ext_vector_type(4))) unsigned short;

// ---------------------------------------------------------------------------
// Static workspace
__device__ float g_x[TD];                  // residual stream fp32
__device__ u16   g_h[TD];                  // LN out / attn out bf16
__device__ u16   g_q[TD];                  // Q bf16 [TOK][D]
__device__ u16   g_k[TD];                  // K bf16 [TOK][D]
__device__ u16   g_vt[TD];                 // V^T bf16 [B][H][DK][S]
__device__ u16   g_ffn[(size_t)TOK * DFF]; // FFN act bf16
__device__ u16   g_qkvT[(size_t)L * 3 * D * D];   // [L][1536][512]
__device__ u16   g_woT[(size_t)L * D * D];        // [L][512][512]
__device__ u16   g_w1T[(size_t)L * DFF * D];      // [L][2048][512]
__device__ u16   g_w2T[(size_t)L * D * DFF];      // [L][512][2048]
__device__ float g_bqkv[L * 3 * D];               // [L][1536]

__device__ __forceinline__ u16 f2bf(float f) {
  unsigned int u = __builtin_bit_cast(unsigned int, f);
  u = (u + 0x7fffu + ((u >> 16) & 1u)) >> 16;
  return (u16)u;
}

__device__ __forceinline__ void gld16(const void* g, void* l) {
  __builtin_amdgcn_global_load_lds(
      (const __attribute__((address_space(1))) unsigned int*)g,
      (__attribute__((address_space(3))) unsigned int*)l, 16, 0, 0);
}

// ---------------------------------------------------------------------------
// Embedding + intensity projection (fp32 residual stream)
__global__ __launch_bounds__(256) void embed_kernel(
    const int* __restrict__ ids, const float* __restrict__ inten,
    const float* __restrict__ emb, const float* __restrict__ iw,
    const float* __restrict__ ib, float* __restrict__ x) {
  int tok = blockIdx.x;
  int t = threadIdx.x;
  int id = ids[tok];
  float it = inten[tok];
  const float* er = emb + (size_t)id * D;
  float* xr = x + (size_t)tok * D;
  xr[t] = er[t] + it * iw[t] + ib[t];
  xr[t + 256] = er[t + 256] + it * iw[t + 256] + ib[t + 256];
}

// ---------------------------------------------------------------------------
// LayerNorm fp32 -> bf16
__global__ __launch_bounds__(256) void ln_kernel(
    const float* __restrict__ x, const float* __restrict__ w,
    const float* __restrict__ b, u16* __restrict__ out) {
  int tok = blockIdx.x;
  int t = threadIdx.x;
  const float* xr = x + (size_t)tok * D;
  float v0 = xr[t], v1 = xr[t + 256];
  float s = v0 + v1;
  float ss = v0 * v0 + v1 * v1;
  #pragma unroll
  for (int off = 32; off >= 1; off >>= 1) {
    s += __shfl_down(s, off);
    ss += __shfl_down(ss, off);
  }
  __shared__ float sbuf[4], ssbuf[4];
  int wave = t >> 6, lane = t & 63;
  if (lane == 0) { sbuf[wave] = s; ssbuf[wave] = ss; }
  __syncthreads();
  s = sbuf[0] + sbuf[1] + sbuf[2] + sbuf[3];
  ss = ssbuf[0] + ssbuf[1] + ssbuf[2] + ssbuf[3];
  float mean = s * (1.0f / (float)D);
  float var = ss * (1.0f / (float)D) - mean * mean;
  float rstd = rsqrtf(var + 1e-5f);
  u16* orow = out + (size_t)tok * D;
  orow[t]       = f2bf((v0 - mean) * rstd * w[t] + b[t]);
  orow[t + 256] = f2bf((v1 - mean) * rstd * w[t + 256] + b[t + 256]);
}

// ---------------------------------------------------------------------------
// Weight transpose+convert: src fp32 [K][N] -> dst bf16 [N][K]
__global__ __launch_bounds__(256) void transpose_cvt(
    const float* __restrict__ src, u16* __restrict__ dst,
    int K, int N, size_t sstride, size_t dstride) {
  __shared__ float tile[32][33];
  int n0 = blockIdx.x * 32, k0 = blockIdx.y * 32, l = blockIdx.z;
  src += (size_t)l * sstride;
  dst += (size_t)l * dstride;
  int tx = threadIdx.x & 31, ty = threadIdx.x >> 5;  // ty 0..7
  #pragma unroll
  for (int i = 0; i < 32; i += 8)
    tile[ty + i][tx] = src[(size_t)(k0 + ty + i) * N + n0 + tx];
  __syncthreads();
  #pragma unroll
  for (int i = 0; i < 32; i += 8)
    dst[(size_t)(n0 + ty + i) * K + k0 + tx] = f2bf(tile[tx][ty + i]);
}

__global__ __launch_bounds__(256) void concat_bias(
    const float* __restrict__ bq, const float* __restrict__ bk,
    const float* __restrict__ bv, float* __restrict__ dst) {
  int i = blockIdx.x * 256 + threadIdx.x;  // L*1536
  int l = i / 1536, c = i % 1536;
  float v = (c < 512) ? bq[l * 512 + c]
          : (c < 1024) ? bk[l * 512 + c - 512]
                       : bv[l * 512 + c - 1024];
  dst[i] = v;
}

// ---------------------------------------------------------------------------
// MFMA bf16 GEMM: C[M,N] = A[M,K] @ Bt[N,K]^T   (m97 structure, 128x128x32)
// EPI 0: QKV split -> q bf16, k bf16, v^T bf16 (N=1536)
// EPI 1: residual fp32: Cres += acc + bias
// EPI 2: gelu -> bf16 (Oq)
template <int EPI>
__global__ __launch_bounds__(256) void mfma_gemm(
    const u16* __restrict__ A, const u16* __restrict__ Bt,
    const float* __restrict__ bias, float* __restrict__ Cres,
    u16* __restrict__ Oq, u16* __restrict__ Ok, u16* __restrict__ Ovt,
    int M, int N, int K) {
  __shared__ u16 As[128 * 32];
  __shared__ u16 Bs[128 * 32];
  int t = threadIdx.x;
  int lane = t & 63, w = t >> 6;
  int wr = w >> 1, wc = w & 1;
  int bm = blockIdx.y * 128, bn = blockIdx.x * 128;
  int l15 = lane & 15, l4 = lane >> 4;

  const u16* a0 = A + (size_t)(bm + (t >> 2)) * K + (t & 3) * 8;
  const u16* a1 = A + (size_t)(bm + 64 + (t >> 2)) * K + (t & 3) * 8;
  const u16* b0 = Bt + (size_t)(bn + (t >> 2)) * K + (t & 3) * 8;
  const u16* b1 = Bt + (size_t)(bn + 64 + (t >> 2)) * K + (t & 3) * 8;
  unsigned off0 = (unsigned)(t & 192) * 16u;          // wave-uniform byte base
  unsigned off1 = off0 + 256u * 16u;

  f32x4 acc[4][4];
  #pragma unroll
  for (int mi = 0; mi < 4; ++mi)
    #pragma unroll
    for (int nj = 0; nj < 4; ++nj)
      acc[mi][nj] = f32x4{0.f, 0.f, 0.f, 0.f};

  for (int k0 = 0; k0 < K; k0 += 32) {
    gld16(a0 + k0, (char*)As + off0);
    gld16(a1 + k0, (char*)As + off1);
    gld16(b0 + k0, (char*)Bs + off0);
    gld16(b1 + k0, (char*)Bs + off1);
    __syncthreads();
    bf16x8 af[4], bfr[4];
    #pragma unroll
    for (int mi = 0; mi < 4; ++mi)
      af[mi] = *(const bf16x8*)(As + (wr * 64 + mi * 16 + l15) * 32 + l4 * 8);
    #pragma unroll
    for (int nj = 0; nj < 4; ++nj)
      bfr[nj] = *(const bf16x8*)(Bs + (wc * 64 + nj * 16 + l15) * 32 + l4 * 8);
    #pragma unroll
    for (int mi = 0; mi < 4; ++mi)
      #pragma unroll
      for (int nj = 0; nj < 4; ++nj)
        acc[mi][nj] = __builtin_amdgcn_mfma_f32_16x16x32_bf16(af[mi], bfr[nj], acc[mi][nj], 0, 0, 0);
    __syncthreads();
  }

  int row00 = bm + wr * 64, col0 = bn + wc * 64;
  #pragma unroll
  for (int mi = 0; mi < 4; ++mi) {
    int rowb = row00 + mi * 16 + l4 * 4;
    #pragma unroll
    for (int nj = 0; nj < 4; ++nj) {
      int col = col0 + nj * 16 + l15;
      float bcol = bias[col];
      if (EPI == 0) {
        if (col < 512) {
          #pragma unroll
          for (int r = 0; r < 4; ++r)
            Oq[(size_t)(rowb + r) * D + col] = f2bf(acc[mi][nj][r] + bcol);
        } else if (col < 1024) {
          #pragma unroll
          for (int r = 0; r < 4; ++r)
            Ok[(size_t)(rowb + r) * D + (col - 512)] = f2bf(acc[mi][nj][r] + bcol);
        } else {
          int cv = col - 1024;
          int hh = cv >> 6, dk = cv & 63;
          int bb = rowb / S, ss = rowb - bb * S;
          u16x4 pk;
          #pragma unroll
          for (int r = 0; r < 4; ++r) pk[r] = f2bf(acc[mi][nj][r] + bcol);
          *(u16x4*)(Ovt + ((size_t)(bb * H + hh) * DK + dk) * S + ss) = pk;
        }
      } else if (EPI == 1) {
        #pragma unroll
        for (int r = 0; r < 4; ++r) {
          size_t ci = (size_t)(rowb + r) * N + col;
          Cres[ci] += acc[mi][nj][r] + bcol;
        }
      } else {  // GELU -> bf16
        #pragma unroll
        for (int r = 0; r < 4; ++r) {
          float v = acc[mi][nj][r] + bcol;
          v = 0.5f * v * (1.0f + erff(v * 0.70710678118654752f));
          Oq[(size_t)(rowb + r) * N + col] = f2bf(v);
        }
      }
    }
  }
}

// ---------------------------------------------------------------------------
// MFMA flash attention. Grid: (B*H, S/128). 4 waves x 32 queries.
__global__ __launch_bounds__(256) void attn_mfma(
    const u16* __restrict__ q, const u16* __restrict__ k,
    const u16* __restrict__ vt, const int* __restrict__ ids,
    u16* __restrict__ out) {
  __shared__ u16 Ks[64][72];
  __shared__ u16 Vs[64][72];   // V^T tile: [dk][key]
  __shared__ u16 Ps[4][32][72];
  __shared__ float Ms[64];
  int t = threadIdx.x, lane = t & 63, w = t >> 6;
  int l15 = lane & 15, l4 = lane >> 4;
  int bh = blockIdx.x;
  int b = bh >> 3, hh = bh & 7;
  int q0 = blockIdx.y * 128 + w * 32;

  // Preload Q fragments (2 m-frags x 2 k-steps)
  bf16x8 qf[2][2];
  const u16* qbase = q + (size_t)(b * S + q0) * D + hh * DK;
  #pragma unroll
  for (int mi = 0; mi < 2; ++mi)
    #pragma unroll
    for (int ks = 0; ks < 2; ++ks)
      qf[mi][ks] = *(const bf16x8*)(qbase + (size_t)(mi * 16 + l15) * D + ks * 32 + l4 * 8);

  float m[8], lsum[8];
  f32x4 accO[2][4];
  #pragma unroll
  for (int i = 0; i < 8; ++i) { m[i] = -3e38f; lsum[i] = 0.f; }
  #pragma unroll
  for (int mi = 0; mi < 2; ++mi)
    #pragma unroll
    for (int nj = 0; nj < 4; ++nj)
      accO[mi][nj] = f32x4{0.f, 0.f, 0.f, 0.f};

  for (int kb = 0; kb < S; kb += 64) {
    __syncthreads();
    #pragma unroll
    for (int i = 0; i < 2; ++i) {
      int slot = i * 256 + t;
      int rr = slot >> 3, ch = slot & 7;
      *(bf16x8*)(&Ks[rr][ch * 8]) =
          *(const bf16x8*)(k + (size_t)(b * S + kb + rr) * D + hh * DK + ch * 8);
      *(bf16x8*)(&Vs[rr][ch * 8]) =
          *(const bf16x8*)(vt + ((size_t)(b * H + hh) * DK + rr) * S + kb + ch * 8);
    }
    if (t < 64) Ms[t] = (ids[b * S + kb + t] == 0) ? -1e9f : 0.0f;
    __syncthreads();

    // QK^T
    f32x4 sc[2][4];
    #pragma unroll
    for (int mi = 0; mi < 2; ++mi)
      #pragma unroll
      for (int nj = 0; nj < 4; ++nj)
        sc[mi][nj] = f32x4{0.f, 0.f, 0.f, 0.f};
    #pragma unroll
    for (int ks = 0; ks < 2; ++ks) {
      bf16x8 kf[4];
      #pragma unroll
      for (int nj = 0; nj < 4; ++nj)
        kf[nj] = *(const bf16x8*)(&Ks[nj * 16 + l15][ks * 32 + l4 * 8]);
      #pragma unroll
      for (int mi = 0; mi < 2; ++mi)
        #pragma unroll
        for (int nj = 0; nj < 4; ++nj)
          sc[mi][nj] = __builtin_amdgcn_mfma_f32_16x16x32_bf16(qf[mi][ks], kf[nj], sc[mi][nj], 0, 0, 0);
    }
    // scale + mask
    #pragma unroll
    for (int mi = 0; mi < 2; ++mi)
      #pragma unroll
      for (int nj = 0; nj < 4; ++nj) {
        float mv = Ms[nj * 16 + l15];
        #pragma unroll
        for (int r = 0; r < 4; ++r)
          sc[mi][nj][r] = sc[mi][nj][r] * 0.125f + mv;
      }
    // online softmax (rows live in lanes with same l4)
    #pragma unroll
    for (int mi = 0; mi < 2; ++mi)
      #pragma unroll
      for (int r = 0; r < 4; ++r) {
        int ridx = mi * 4 + r;
        float mx = sc[mi][0][r];
        #pragma unroll
        for (int nj = 1; nj < 4; ++nj) mx = fmaxf(mx, sc[mi][nj][r]);
        #pragma unroll
        for (int o = 1; o < 16; o <<= 1) mx = fmaxf(mx, __shfl_xor(mx, o));
        float mnew = fmaxf(m[ridx], mx);
        float scale = __expf(m[ridx] - mnew);
        float rs = 0.f;
        #pragma unroll
        for (int nj = 0; nj < 4; ++nj) {
          float p = __expf(sc[mi][nj][r] - mnew);
          sc[mi][nj][r] = p;
          rs += p;
        }
        #pragma unroll
        for (int o = 1; o < 16; o <<= 1) rs += __shfl_xor(rs, o);
        lsum[ridx] = lsum[ridx] * scale + rs;
        m[ridx] = mnew;
        #pragma unroll
        for (int nj = 0; nj < 4; ++nj) accO[mi][nj][r] *= scale;
      }
    // P -> bf16 -> wave-private LDS
    #pragma unroll
    for (int mi = 0; mi < 2; ++mi)
      #pragma unroll
      for (int nj = 0; nj < 4; ++nj)
        #pragma unroll
        for (int r = 0; r < 4; ++r)
          Ps[w][mi * 16 + l4 * 4 + r][nj * 16 + l15] = f2bf(sc[mi][nj][r]);
    // PV
    #pragma unroll
    for (int ks2 = 0; ks2 < 2; ++ks2) {
      bf16x8 pf[2], vf[4];
      #pragma unroll
      for (int mi = 0; mi < 2; ++mi)
        pf[mi] = *(const bf16x8*)(&Ps[w][mi * 16 + l15][ks2 * 32 + l4 * 8]);
      #pragma unroll
      for (int nj = 0; nj < 4; ++nj)
        vf[nj] = *(const bf16x8*)(&Vs[nj * 16 + l15][ks2 * 32 + l4 * 8]);
      #pragma unroll
      for (int mi = 0; mi < 2; ++mi)
        #pragma unroll
        for (int nj = 0; nj < 4; ++nj)
          accO[mi][nj] = __builtin_amdgcn_mfma_f32_16x16x32_bf16(pf[mi], vf[nj], accO[mi][nj], 0, 0, 0);
    }
  }

  // output bf16 [TOK][D]
  #pragma unroll
  for (int mi = 0; mi < 2; ++mi)
    #pragma unroll
    for (int nj = 0; nj < 4; ++nj)
      #pragma unroll
      for (int r = 0; r < 4; ++r) {
        int row = b * S + q0 + mi * 16 + l4 * 4 + r;
        out[(size_t)row * D + hh * DK + nj * 16 + l15] =
            f2bf(accO[mi][nj][r] / lsum[mi * 4 + r]);
      }
}

// ---------------------------------------------------------------------------
__global__ __launch_bounds__(512) void pool_kernel(
    const float* __restrict__ x, const float* __restrict__ inten,
    float* __restrict__ out) {
  int b = blockIdx.x;
  int d = threadIdx.x;
  float acc = 0.f;
  for (int s = 0; s < S; ++s)
    acc += inten[b * S + s] * x[((size_t)b * S + s) * D + d];
  out[b * D + d] = acc;
}

// ---------------------------------------------------------------------------
extern "C" void kernel_launch(void* const* d_in, const int* in_sizes, int n_in,
                              void* d_out, int out_size, void* d_ws, size_t ws_size,
                              hipStream_t stream) {
  const int* input_id    = (const int*)d_in[0];
  const float* intensity = (const float*)d_in[1];
  const float* emb = (const float*)d_in[2];
  const float* iw  = (const float*)d_in[3];
  const float* ib  = (const float*)d_in[4];
  const float* Wq  = (const float*)d_in[5];
  const float* bq  = (const float*)d_in[6];
  const float* Wk  = (const float*)d_in[7];
  const float* bk  = (const float*)d_in[8];
  const float* Wv  = (const float*)d_in[9];
  const float* bv  = (const float*)d_in[10];
  const float* Wo  = (const float*)d_in[11];
  const float* bo  = (const float*)d_in[12];
  const float* ln1w = (const float*)d_in[13];
  const float* ln1b = (const float*)d_in[14];
  const float* ln2w = (const float*)d_in[15];
  const float* ln2b = (const float*)d_in[16];
  const float* W1  = (const float*)d_in[17];
  const float* b1  = (const float*)d_in[18];
  const float* W2  = (const float*)d_in[19];
  const float* b2  = (const float*)d_in[20];
  float* outp = (float*)d_out;

  float *x, *bqkv;
  u16 *h, *q, *k, *vt, *ffn, *qkvT, *woT, *w1T, *w2T;
  { void* p; hipGetSymbolAddress(&p, HIP_SYMBOL(g_x));    x    = (float*)p; }
  { void* p; hipGetSymbolAddress(&p, HIP_SYMBOL(g_h));    h    = (u16*)p; }
  { void* p; hipGetSymbolAddress(&p, HIP_SYMBOL(g_q));    q    = (u16*)p; }
  { void* p; hipGetSymbolAddress(&p, HIP_SYMBOL(g_k));    k    = (u16*)p; }
  { void* p; hipGetSymbolAddress(&p, HIP_SYMBOL(g_vt));   vt   = (u16*)p; }
  { void* p; hipGetSymbolAddress(&p, HIP_SYMBOL(g_ffn));  ffn  = (u16*)p; }
  { void* p; hipGetSymbolAddress(&p, HIP_SYMBOL(g_qkvT)); qkvT = (u16*)p; }
  { void* p; hipGetSymbolAddress(&p, HIP_SYMBOL(g_woT));  woT  = (u16*)p; }
  { void* p; hipGetSymbolAddress(&p, HIP_SYMBOL(g_w1T));  w1T  = (u16*)p; }
  { void* p; hipGetSymbolAddress(&p, HIP_SYMBOL(g_w2T));  w2T  = (u16*)p; }
  { void* p; hipGetSymbolAddress(&p, HIP_SYMBOL(g_bqkv)); bqkv = (float*)p; }

  // ---- weight prep (per launch; deterministic) ----
  dim3 t256(256);
  transpose_cvt<<<dim3(16, 16, L), t256, 0, stream>>>(Wq, qkvT + 0 * D * D, D, D, (size_t)D * D, (size_t)3 * D * D);
  transpose_cvt<<<dim3(16, 16, L), t256, 0, stream>>>(Wk, qkvT + 1 * D * D, D, D, (size_t)D * D, (size_t)3 * D * D);
  transpose_cvt<<<dim3(16, 16, L), t256, 0, stream>>>(Wv, qkvT + 2 * D * D, D, D, (size_t)D * D, (size_t)3 * D * D);
  transpose_cvt<<<dim3(16, 16, L), t256, 0, stream>>>(Wo, woT, D, D, (size_t)D * D, (size_t)D * D);
  transpose_cvt<<<dim3(64, 16, L), t256, 0, stream>>>(W1, w1T, D, DFF, (size_t)D * DFF, (size_t)D * DFF);
  transpose_cvt<<<dim3(16, 64, L), t256, 0, stream>>>(W2, w2T, DFF, D, (size_t)DFF * D, (size_t)DFF * D);
  concat_bias<<<L * 3 * D / 256, t256, 0, stream>>>(bq, bk, bv, bqkv);

  embed_kernel<<<TOK, t256, 0, stream>>>(input_id, intensity, emb, iw, ib, x);

  for (int l = 0; l < L; ++l) {
    const u16* qkvT_l = qkvT + (size_t)l * 3 * D * D;
    const u16* woT_l  = woT + (size_t)l * D * D;
    const u16* w1T_l  = w1T + (size_t)l * D * DFF;
    const u16* w2T_l  = w2T + (size_t)l * DFF * D;

    ln_kernel<<<TOK, t256, 0, stream>>>(x, ln1w + (size_t)l * D, ln1b + (size_t)l * D, h);
    mfma_gemm<0><<<dim3(12, 96), t256, 0, stream>>>(h, qkvT_l, bqkv + l * 3 * D,
                                                    nullptr, q, k, vt, TOK, 3 * D, D);
    attn_mfma<<<dim3(B * H, S / 128), t256, 0, stream>>>(q, k, vt, input_id, h);
    mfma_gemm<1><<<dim3(4, 96), t256, 0, stream>>>(h, woT_l, bo + (size_t)l * D,
                                                   x, nullptr, nullptr, nullptr, TOK, D, D);
    ln_kernel<<<TOK, t256, 0, stream>>>(x, ln2w + (size_t)l * D, ln2b + (size_t)l * D, h);
    mfma_gemm<2><<<dim3(16, 96), t256, 0, stream>>>(h, w1T_l, b1 + (size_t)l * DFF,
                                                    nullptr, ffn, nullptr, nullptr, TOK, DFF, D);
    mfma_gemm<1><<<dim3(4, 96), t256, 0, stream>>>(ffn, w2T_l, b2 + (size_t)l * D,
                                                   x, nullptr, nullptr, nullptr, TOK, D, DFF);
  }

  pool_kernel<<<B, 512, 0, stream>>>(x, intensity, outp);
}

// Round 3
// 1517.156 us; speedup vs baseline: 6.7709x; 1.2216x over previous
//
#include <hip/hip_runtime.h>
#include <math.h>

// Problem constants
#define VOCAB 10000
#define D 512
#define L 6
#define H 8
#define B 32
#define S 384
#define DK 64
#define DFF 2048
#define TOK (B * S)            // 12288 tokens
#define TD ((size_t)TOK * D)   // 6291456 elements per activation buffer

typedef unsigned short u16;
using bf16x8 = __attribute__((ext_vector_type(8))) short;
using f32x4  = __attribute__((ext_vector_type(4))) float;
using u16x4  = __attribute__((ext_vector_type(4))) unsigned short;

// ---------------------------------------------------------------------------
// Static workspace
__device__ float g_x[TD];                  // residual stream fp32
__device__ u16   g_h[TD];                  // LN out / attn out bf16
__device__ u16   g_q[TD];                  // Q bf16 [TOK][D]
__device__ u16   g_k[TD];                  // K bf16 [TOK][D]
__device__ u16   g_vt[TD];                 // V^T bf16 [B][H][DK][S]
__device__ u16   g_ffn[(size_t)TOK * DFF]; // FFN act bf16
__device__ u16   g_qkvT[(size_t)L * 3 * D * D];   // [L][1536][512]
__device__ u16   g_woT[(size_t)L * D * D];        // [L][512][512]
__device__ u16   g_w1T[(size_t)L * DFF * D];      // [L][2048][512]
__device__ u16   g_w2T[(size_t)L * D * DFF];      // [L][512][2048]
__device__ float g_bqkv[L * 3 * D];               // [L][1536]

__device__ __forceinline__ u16 f2bf(float f) {
  unsigned int u = __builtin_bit_cast(unsigned int, f);
  u = (u + 0x7fffu + ((u >> 16) & 1u)) >> 16;
  return (u16)u;
}

__device__ __forceinline__ void gld16(const void* g, void* l) {
  __builtin_amdgcn_global_load_lds(
      (const __attribute__((address_space(1))) unsigned int*)g,
      (__attribute__((address_space(3))) unsigned int*)l, 16, 0, 0);
}

// ---------------------------------------------------------------------------
// Embedding + intensity projection (fp32 residual stream)
__global__ __launch_bounds__(256) void embed_kernel(
    const int* __restrict__ ids, const float* __restrict__ inten,
    const float* __restrict__ emb, const float* __restrict__ iw,
    const float* __restrict__ ib, float* __restrict__ x) {
  int tok = blockIdx.x;
  int t = threadIdx.x;
  int id = ids[tok];
  float it = inten[tok];
  const float* er = emb + (size_t)id * D;
  float* xr = x + (size_t)tok * D;
  xr[t] = er[t] + it * iw[t] + ib[t];
  xr[t + 256] = er[t + 256] + it * iw[t + 256] + ib[t + 256];
}

// ---------------------------------------------------------------------------
// LayerNorm fp32 -> bf16
__global__ __launch_bounds__(256) void ln_kernel(
    const float* __restrict__ x, const float* __restrict__ w,
    const float* __restrict__ b, u16* __restrict__ out) {
  int tok = blockIdx.x;
  int t = threadIdx.x;
  const float* xr = x + (size_t)tok * D;
  float v0 = xr[t], v1 = xr[t + 256];
  float s = v0 + v1;
  float ss = v0 * v0 + v1 * v1;
  #pragma unroll
  for (int off = 32; off >= 1; off >>= 1) {
    s += __shfl_down(s, off);
    ss += __shfl_down(ss, off);
  }
  __shared__ float sbuf[4], ssbuf[4];
  int wave = t >> 6, lane = t & 63;
  if (lane == 0) { sbuf[wave] = s; ssbuf[wave] = ss; }
  __syncthreads();
  s = sbuf[0] + sbuf[1] + sbuf[2] + sbuf[3];
  ss = ssbuf[0] + ssbuf[1] + ssbuf[2] + ssbuf[3];
  float mean = s * (1.0f / (float)D);
  float var = ss * (1.0f / (float)D) - mean * mean;
  float rstd = rsqrtf(var + 1e-5f);
  u16* orow = out + (size_t)tok * D;
  orow[t]       = f2bf((v0 - mean) * rstd * w[t] + b[t]);
  orow[t + 256] = f2bf((v1 - mean) * rstd * w[t + 256] + b[t + 256]);
}

// ---------------------------------------------------------------------------
// Weight transpose+convert: src fp32 [K][N] -> dst bf16 [N][K]
__global__ __launch_bounds__(256) void transpose_cvt(
    const float* __restrict__ src, u16* __restrict__ dst,
    int K, int N, size_t sstride, size_t dstride) {
  __shared__ float tile[32][33];
  int n0 = blockIdx.x * 32, k0 = blockIdx.y * 32, l = blockIdx.z;
  src += (size_t)l * sstride;
  dst += (size_t)l * dstride;
  int tx = threadIdx.x & 31, ty = threadIdx.x >> 5;  // ty 0..7
  #pragma unroll
  for (int i = 0; i < 32; i += 8)
    tile[ty + i][tx] = src[(size_t)(k0 + ty + i) * N + n0 + tx];
  __syncthreads();
  #pragma unroll
  for (int i = 0; i < 32; i += 8)
    dst[(size_t)(n0 + ty + i) * K + k0 + tx] = f2bf(tile[tx][ty + i]);
}

__global__ __launch_bounds__(256) void concat_bias(
    const float* __restrict__ bq, const float* __restrict__ bk,
    const float* __restrict__ bv, float* __restrict__ dst) {
  int i = blockIdx.x * 256 + threadIdx.x;  // L*1536
  int l = i / 1536, c = i % 1536;
  float v = (c < 512) ? bq[l * 512 + c]
          : (c < 1024) ? bk[l * 512 + c - 512]
                       : bv[l * 512 + c - 1024];
  dst[i] = v;
}

// ---------------------------------------------------------------------------
// MFMA bf16 GEMM: C[M,N] = A[M,K] @ Bt[N,K]^T   (m97 structure, 128x128x32)
// XCD-chunked swizzle: each XCD owns gm/8 contiguous bm-rows and iterates all
// bn within -> A slab (1.5 MB) + B (<=2 MB) stay resident in its private L2.
// EPI 0: QKV split -> q bf16, k bf16, v^T bf16 (N=1536)
// EPI 1: residual fp32: Cres += acc + bias
// EPI 2: gelu -> bf16 (Oq)
template <int EPI>
__global__ __launch_bounds__(256) void mfma_gemm(
    const u16* __restrict__ A, const u16* __restrict__ Bt,
    const float* __restrict__ bias, float* __restrict__ Cres,
    u16* __restrict__ Oq, u16* __restrict__ Ok, u16* __restrict__ Ovt,
    int M, int N, int K) {
  __shared__ u16 As[128 * 32];
  __shared__ u16 Bs[128 * 32];
  int t = threadIdx.x;
  int lane = t & 63, w = t >> 6;
  int wr = w >> 1, wc = w & 1;

  // ---- XCD-chunked bijective remap (gm % 8 == 0 guaranteed: gm = 96) ----
  int gm = gridDim.y, gn = gridDim.x;
  int wgid = blockIdx.y * gn + blockIdx.x;   // dispatch-linear id
  int xcd = wgid & 7;
  int c = wgid >> 3;
  int rpx = gm >> 3;                          // bm-rows per XCD
  int cg = c / gn;
  int bmi = xcd * rpx + cg;
  int bni = c - cg * gn;
  int bm = bmi * 128, bn = bni * 128;

  int l15 = lane & 15, l4 = lane >> 4;

  const u16* a0 = A + (size_t)(bm + (t >> 2)) * K + (t & 3) * 8;
  const u16* a1 = A + (size_t)(bm + 64 + (t >> 2)) * K + (t & 3) * 8;
  const u16* b0 = Bt + (size_t)(bn + (t >> 2)) * K + (t & 3) * 8;
  const u16* b1 = Bt + (size_t)(bn + 64 + (t >> 2)) * K + (t & 3) * 8;
  unsigned off0 = (unsigned)(t & 192) * 16u;          // wave-uniform byte base
  unsigned off1 = off0 + 256u * 16u;

  f32x4 acc[4][4];
  #pragma unroll
  for (int mi = 0; mi < 4; ++mi)
    #pragma unroll
    for (int nj = 0; nj < 4; ++nj)
      acc[mi][nj] = f32x4{0.f, 0.f, 0.f, 0.f};

  for (int k0 = 0; k0 < K; k0 += 32) {
    gld16(a0 + k0, (char*)As + off0);
    gld16(a1 + k0, (char*)As + off1);
    gld16(b0 + k0, (char*)Bs + off0);
    gld16(b1 + k0, (char*)Bs + off1);
    __syncthreads();
    bf16x8 af[4], bfr[4];
    #pragma unroll
    for (int mi = 0; mi < 4; ++mi)
      af[mi] = *(const bf16x8*)(As + (wr * 64 + mi * 16 + l15) * 32 + l4 * 8);
    #pragma unroll
    for (int nj = 0; nj < 4; ++nj)
      bfr[nj] = *(const bf16x8*)(Bs + (wc * 64 + nj * 16 + l15) * 32 + l4 * 8);
    #pragma unroll
    for (int mi = 0; mi < 4; ++mi)
      #pragma unroll
      for (int nj = 0; nj < 4; ++nj)
        acc[mi][nj] = __builtin_amdgcn_mfma_f32_16x16x32_bf16(af[mi], bfr[nj], acc[mi][nj], 0, 0, 0);
    __syncthreads();
  }

  int row00 = bm + wr * 64, col0 = bn + wc * 64;
  #pragma unroll
  for (int mi = 0; mi < 4; ++mi) {
    int rowb = row00 + mi * 16 + l4 * 4;
    #pragma unroll
    for (int nj = 0; nj < 4; ++nj) {
      int col = col0 + nj * 16 + l15;
      float bcol = bias[col];
      if (EPI == 0) {
        if (col < 512) {
          #pragma unroll
          for (int r = 0; r < 4; ++r)
            Oq[(size_t)(rowb + r) * D + col] = f2bf(acc[mi][nj][r] + bcol);
        } else if (col < 1024) {
          #pragma unroll
          for (int r = 0; r < 4; ++r)
            Ok[(size_t)(rowb + r) * D + (col - 512)] = f2bf(acc[mi][nj][r] + bcol);
        } else {
          int cv = col - 1024;
          int hh = cv >> 6, dk = cv & 63;
          int bb = rowb / S, ss = rowb - bb * S;
          u16x4 pk;
          #pragma unroll
          for (int r = 0; r < 4; ++r) pk[r] = f2bf(acc[mi][nj][r] + bcol);
          *(u16x4*)(Ovt + ((size_t)(bb * H + hh) * DK + dk) * S + ss) = pk;
        }
      } else if (EPI == 1) {
        #pragma unroll
        for (int r = 0; r < 4; ++r) {
          size_t ci = (size_t)(rowb + r) * N + col;
          Cres[ci] += acc[mi][nj][r] + bcol;
        }
      } else {  // GELU -> bf16
        #pragma unroll
        for (int r = 0; r < 4; ++r) {
          float v = acc[mi][nj][r] + bcol;
          v = 0.5f * v * (1.0f + erff(v * 0.70710678118654752f));
          Oq[(size_t)(rowb + r) * N + col] = f2bf(v);
        }
      }
    }
  }
}

// ---------------------------------------------------------------------------
// MFMA flash attention. Grid: (B*H, S/128). 4 waves x 32 queries.
__global__ __launch_bounds__(256) void attn_mfma(
    const u16* __restrict__ q, const u16* __restrict__ k,
    const u16* __restrict__ vt, const int* __restrict__ ids,
    u16* __restrict__ out) {
  __shared__ u16 Ks[64][72];
  __shared__ u16 Vs[64][72];   // V^T tile: [dk][key]
  __shared__ u16 Ps[4][32][72];
  __shared__ float Ms[64];
  int t = threadIdx.x, lane = t & 63, w = t >> 6;
  int l15 = lane & 15, l4 = lane >> 4;
  int bh = blockIdx.x;
  int b = bh >> 3, hh = bh & 7;
  int q0 = blockIdx.y * 128 + w * 32;

  // Preload Q fragments (2 m-frags x 2 k-steps)
  bf16x8 qf[2][2];
  const u16* qbase = q + (size_t)(b * S + q0) * D + hh * DK;
  #pragma unroll
  for (int mi = 0; mi < 2; ++mi)
    #pragma unroll
    for (int ks = 0; ks < 2; ++ks)
      qf[mi][ks] = *(const bf16x8*)(qbase + (size_t)(mi * 16 + l15) * D + ks * 32 + l4 * 8);

  float m[8], lsum[8];
  f32x4 accO[2][4];
  #pragma unroll
  for (int i = 0; i < 8; ++i) { m[i] = -3e38f; lsum[i] = 0.f; }
  #pragma unroll
  for (int mi = 0; mi < 2; ++mi)
    #pragma unroll
    for (int nj = 0; nj < 4; ++nj)
      accO[mi][nj] = f32x4{0.f, 0.f, 0.f, 0.f};

  for (int kb = 0; kb < S; kb += 64) {
    __syncthreads();
    #pragma unroll
    for (int i = 0; i < 2; ++i) {
      int slot = i * 256 + t;
      int rr = slot >> 3, ch = slot & 7;
      *(bf16x8*)(&Ks[rr][ch * 8]) =
          *(const bf16x8*)(k + (size_t)(b * S + kb + rr) * D + hh * DK + ch * 8);
      *(bf16x8*)(&Vs[rr][ch * 8]) =
          *(const bf16x8*)(vt + ((size_t)(b * H + hh) * DK + rr) * S + kb + ch * 8);
    }
    if (t < 64) Ms[t] = (ids[b * S + kb + t] == 0) ? -1e9f : 0.0f;
    __syncthreads();

    // QK^T
    f32x4 sc[2][4];
    #pragma unroll
    for (int mi = 0; mi < 2; ++mi)
      #pragma unroll
      for (int nj = 0; nj < 4; ++nj)
        sc[mi][nj] = f32x4{0.f, 0.f, 0.f, 0.f};
    #pragma unroll
    for (int ks = 0; ks < 2; ++ks) {
      bf16x8 kf[4];
      #pragma unroll
      for (int nj = 0; nj < 4; ++nj)
        kf[nj] = *(const bf16x8*)(&Ks[nj * 16 + l15][ks * 32 + l4 * 8]);
      #pragma unroll
      for (int mi = 0; mi < 2; ++mi)
        #pragma unroll
        for (int nj = 0; nj < 4; ++nj)
          sc[mi][nj] = __builtin_amdgcn_mfma_f32_16x16x32_bf16(qf[mi][ks], kf[nj], sc[mi][nj], 0, 0, 0);
    }
    // scale + mask
    #pragma unroll
    for (int mi = 0; mi < 2; ++mi)
      #pragma unroll
      for (int nj = 0; nj < 4; ++nj) {
        float mv = Ms[nj * 16 + l15];
        #pragma unroll
        for (int r = 0; r < 4; ++r)
          sc[mi][nj][r] = sc[mi][nj][r] * 0.125f + mv;
      }
    // online softmax (rows live in lanes with same l4)
    #pragma unroll
    for (int mi = 0; mi < 2; ++mi)
      #pragma unroll
      for (int r = 0; r < 4; ++r) {
        int ridx = mi * 4 + r;
        float mx = sc[mi][0][r];
        #pragma unroll
        for (int nj = 1; nj < 4; ++nj) mx = fmaxf(mx, sc[mi][nj][r]);
        #pragma unroll
        for (int o = 1; o < 16; o <<= 1) mx = fmaxf(mx, __shfl_xor(mx, o));
        float mnew = fmaxf(m[ridx], mx);
        float scale = __expf(m[ridx] - mnew);
        float rs = 0.f;
        #pragma unroll
        for (int nj = 0; nj < 4; ++nj) {
          float p = __expf(sc[mi][nj][r] - mnew);
          sc[mi][nj][r] = p;
          rs += p;
        }
        #pragma unroll
        for (int o = 1; o < 16; o <<= 1) rs += __shfl_xor(rs, o);
        lsum[ridx] = lsum[ridx] * scale + rs;
        m[ridx] = mnew;
        #pragma unroll
        for (int nj = 0; nj < 4; ++nj) accO[mi][nj][r] *= scale;
      }
    // P -> bf16 -> wave-private LDS
    #pragma unroll
    for (int mi = 0; mi < 2; ++mi)
      #pragma unroll
      for (int nj = 0; nj < 4; ++nj)
        #pragma unroll
        for (int r = 0; r < 4; ++r)
          Ps[w][mi * 16 + l4 * 4 + r][nj * 16 + l15] = f2bf(sc[mi][nj][r]);
    // PV
    #pragma unroll
    for (int ks2 = 0; ks2 < 2; ++ks2) {
      bf16x8 pf[2], vf[4];
      #pragma unroll
      for (int mi = 0; mi < 2; ++mi)
        pf[mi] = *(const bf16x8*)(&Ps[w][mi * 16 + l15][ks2 * 32 + l4 * 8]);
      #pragma unroll
      for (int nj = 0; nj < 4; ++nj)
        vf[nj] = *(const bf16x8*)(&Vs[nj * 16 + l15][ks2 * 32 + l4 * 8]);
      #pragma unroll
      for (int mi = 0; mi < 2; ++mi)
        #pragma unroll
        for (int nj = 0; nj < 4; ++nj)
          accO[mi][nj] = __builtin_amdgcn_mfma_f32_16x16x32_bf16(pf[mi], vf[nj], accO[mi][nj], 0, 0, 0);
    }
  }

  // output bf16 [TOK][D]
  #pragma unroll
  for (int mi = 0; mi < 2; ++mi)
    #pragma unroll
    for (int nj = 0; nj < 4; ++nj)
      #pragma unroll
      for (int r = 0; r < 4; ++r) {
        int row = b * S + q0 + mi * 16 + l4 * 4 + r;
        out[(size_t)row * D + hh * DK + nj * 16 + l15] =
            f2bf(accO[mi][nj][r] / lsum[mi * 4 + r]);
      }
}

// ---------------------------------------------------------------------------
__global__ __launch_bounds__(512) void pool_kernel(
    const float* __restrict__ x, const float* __restrict__ inten,
    float* __restrict__ out) {
  int b = blockIdx.x;
  int d = threadIdx.x;
  float acc = 0.f;
  for (int s = 0; s < S; ++s)
    acc += inten[b * S + s] * x[((size_t)b * S + s) * D + d];
  out[b * D + d] = acc;
}

// ---------------------------------------------------------------------------
extern "C" void kernel_launch(void* const* d_in, const int* in_sizes, int n_in,
                              void* d_out, int out_size, void* d_ws, size_t ws_size,
                              hipStream_t stream) {
  const int* input_id    = (const int*)d_in[0];
  const float* intensity = (const float*)d_in[1];
  const float* emb = (const float*)d_in[2];
  const float* iw  = (const float*)d_in[3];
  const float* ib  = (const float*)d_in[4];
  const float* Wq  = (const float*)d_in[5];
  const float* bq  = (const float*)d_in[6];
  const float* Wk  = (const float*)d_in[7];
  const float* bk  = (const float*)d_in[8];
  const float* Wv  = (const float*)d_in[9];
  const float* bv  = (const float*)d_in[10];
  const float* Wo  = (const float*)d_in[11];
  const float* bo  = (const float*)d_in[12];
  const float* ln1w = (const float*)d_in[13];
  const float* ln1b = (const float*)d_in[14];
  const float* ln2w = (const float*)d_in[15];
  const float* ln2b = (const float*)d_in[16];
  const float* W1  = (const float*)d_in[17];
  const float* b1  = (const float*)d_in[18];
  const float* W2  = (const float*)d_in[19];
  const float* b2  = (const float*)d_in[20];
  float* outp = (float*)d_out;

  float *x, *bqkv;
  u16 *h, *q, *k, *vt, *ffn, *qkvT, *woT, *w1T, *w2T;
  { void* p; hipGetSymbolAddress(&p, HIP_SYMBOL(g_x));    x    = (float*)p; }
  { void* p; hipGetSymbolAddress(&p, HIP_SYMBOL(g_h));    h    = (u16*)p; }
  { void* p; hipGetSymbolAddress(&p, HIP_SYMBOL(g_q));    q    = (u16*)p; }
  { void* p; hipGetSymbolAddress(&p, HIP_SYMBOL(g_k));    k    = (u16*)p; }
  { void* p; hipGetSymbolAddress(&p, HIP_SYMBOL(g_vt));   vt   = (u16*)p; }
  { void* p; hipGetSymbolAddress(&p, HIP_SYMBOL(g_ffn));  ffn  = (u16*)p; }
  { void* p; hipGetSymbolAddress(&p, HIP_SYMBOL(g_qkvT)); qkvT = (u16*)p; }
  { void* p; hipGetSymbolAddress(&p, HIP_SYMBOL(g_woT));  woT  = (u16*)p; }
  { void* p; hipGetSymbolAddress(&p, HIP_SYMBOL(g_w1T));  w1T  = (u16*)p; }
  { void* p; hipGetSymbolAddress(&p, HIP_SYMBOL(g_w2T));  w2T  = (u16*)p; }
  { void* p; hipGetSymbolAddress(&p, HIP_SYMBOL(g_bqkv)); bqkv = (float*)p; }

  // ---- weight prep (per launch; deterministic) ----
  dim3 t256(256);
  transpose_cvt<<<dim3(16, 16, L), t256, 0, stream>>>(Wq, qkvT + 0 * D * D, D, D, (size_t)D * D, (size_t)3 * D * D);
  transpose_cvt<<<dim3(16, 16, L), t256, 0, stream>>>(Wk, qkvT + 1 * D * D, D, D, (size_t)D * D, (size_t)3 * D * D);
  transpose_cvt<<<dim3(16, 16, L), t256, 0, stream>>>(Wv, qkvT + 2 * D * D, D, D, (size_t)D * D, (size_t)3 * D * D);
  transpose_cvt<<<dim3(16, 16, L), t256, 0, stream>>>(Wo, woT, D, D, (size_t)D * D, (size_t)D * D);
  transpose_cvt<<<dim3(64, 16, L), t256, 0, stream>>>(W1, w1T, D, DFF, (size_t)D * DFF, (size_t)D * DFF);
  transpose_cvt<<<dim3(16, 64, L), t256, 0, stream>>>(W2, w2T, DFF, D, (size_t)DFF * D, (size_t)DFF * D);
  concat_bias<<<L * 3 * D / 256, t256, 0, stream>>>(bq, bk, bv, bqkv);

  embed_kernel<<<TOK, t256, 0, stream>>>(input_id, intensity, emb, iw, ib, x);

  for (int l = 0; l < L; ++l) {
    const u16* qkvT_l = qkvT + (size_t)l * 3 * D * D;
    const u16* woT_l  = woT + (size_t)l * D * D;
    const u16* w1T_l  = w1T + (size_t)l * D * DFF;
    const u16* w2T_l  = w2T + (size_t)l * DFF * D;

    ln_kernel<<<TOK, t256, 0, stream>>>(x, ln1w + (size_t)l * D, ln1b + (size_t)l * D, h);
    mfma_gemm<0><<<dim3(12, 96), t256, 0, stream>>>(h, qkvT_l, bqkv + l * 3 * D,
                                                    nullptr, q, k, vt, TOK, 3 * D, D);
    attn_mfma<<<dim3(B * H, S / 128), t256, 0, stream>>>(q, k, vt, input_id, h);
    mfma_gemm<1><<<dim3(4, 96), t256, 0, stream>>>(h, woT_l, bo + (size_t)l * D,
                                                   x, nullptr, nullptr, nullptr, TOK, D, D);
    ln_kernel<<<TOK, t256, 0, stream>>>(x, ln2w + (size_t)l * D, ln2b + (size_t)l * D, h);
    mfma_gemm<2><<<dim3(16, 96), t256, 0, stream>>>(h, w1T_l, b1 + (size_t)l * DFF,
                                                    nullptr, ffn, nullptr, nullptr, TOK, DFF, D);
    mfma_gemm<1><<<dim3(4, 96), t256, 0, stream>>>(ffn, w2T_l, b2 + (size_t)l * D,
                                                   x, nullptr, nullptr, nullptr, TOK, D, DFF);
  }

  pool_kernel<<<B, 512, 0, stream>>>(x, intensity, outp);
}

// Round 4
// 1453.170 us; speedup vs baseline: 7.0690x; 1.0440x over previous
//
#include <hip/hip_runtime.h>
#include <math.h>

// Problem constants
#define VOCAB 10000
#define D 512
#define L 6
#define H 8
#define B 32
#define S 384
#define DK 64
#define DFF 2048
#define TOK (B * S)            // 12288 tokens
#define TD ((size_t)TOK * D)   // 6291456 elements per activation buffer

typedef unsigned short u16;
using bf16x8 = __attribute__((ext_vector_type(8))) short;
using f32x4  = __attribute__((ext_vector_type(4))) float;
using u16x4  = __attribute__((ext_vector_type(4))) unsigned short;

// ---------------------------------------------------------------------------
// Static workspace
__device__ float g_x[TD];                  // residual stream fp32
__device__ u16   g_h[TD];                  // LN out / attn out bf16
__device__ u16   g_q[TD];                  // Q bf16 [TOK][D]
__device__ u16   g_k[TD];                  // K bf16 [TOK][D]
__device__ u16   g_vt[TD];                 // V^T bf16 [B][H][DK][S]
__device__ u16   g_ffn[(size_t)TOK * DFF]; // FFN act bf16
__device__ u16   g_qkvT[(size_t)L * 3 * D * D];   // [L][1536][512]
__device__ u16   g_woT[(size_t)L * D * D];        // [L][512][512]
__device__ u16   g_w1T[(size_t)L * DFF * D];      // [L][2048][512]
__device__ u16   g_w2T[(size_t)L * D * DFF];      // [L][512][2048]
__device__ float g_bqkv[L * 3 * D];               // [L][1536]

__device__ __forceinline__ u16 f2bf(float f) {
  unsigned int u = __builtin_bit_cast(unsigned int, f);
  u = (u + 0x7fffu + ((u >> 16) & 1u)) >> 16;
  return (u16)u;
}

__device__ __forceinline__ void gld16(const void* g, void* l) {
  __builtin_amdgcn_global_load_lds(
      (const __attribute__((address_space(1))) unsigned int*)g,
      (__attribute__((address_space(3))) unsigned int*)l, 16, 0, 0);
}

// ---------------------------------------------------------------------------
// Embedding + intensity projection (fp32 residual stream)
__global__ __launch_bounds__(256) void embed_kernel(
    const int* __restrict__ ids, const float* __restrict__ inten,
    const float* __restrict__ emb, const float* __restrict__ iw,
    const float* __restrict__ ib, float* __restrict__ x) {
  int tok = blockIdx.x;
  int t = threadIdx.x;
  int id = ids[tok];
  float it = inten[tok];
  const float* er = emb + (size_t)id * D;
  float* xr = x + (size_t)tok * D;
  xr[t] = er[t] + it * iw[t] + ib[t];
  xr[t + 256] = er[t + 256] + it * iw[t + 256] + ib[t + 256];
}

// ---------------------------------------------------------------------------
// LayerNorm fp32 -> bf16
__global__ __launch_bounds__(256) void ln_kernel(
    const float* __restrict__ x, const float* __restrict__ w,
    const float* __restrict__ b, u16* __restrict__ out) {
  int tok = blockIdx.x;
  int t = threadIdx.x;
  const float* xr = x + (size_t)tok * D;
  float v0 = xr[t], v1 = xr[t + 256];
  float s = v0 + v1;
  float ss = v0 * v0 + v1 * v1;
  #pragma unroll
  for (int off = 32; off >= 1; off >>= 1) {
    s += __shfl_down(s, off);
    ss += __shfl_down(ss, off);
  }
  __shared__ float sbuf[4], ssbuf[4];
  int wave = t >> 6, lane = t & 63;
  if (lane == 0) { sbuf[wave] = s; ssbuf[wave] = ss; }
  __syncthreads();
  s = sbuf[0] + sbuf[1] + sbuf[2] + sbuf[3];
  ss = ssbuf[0] + ssbuf[1] + ssbuf[2] + ssbuf[3];
  float mean = s * (1.0f / (float)D);
  float var = ss * (1.0f / (float)D) - mean * mean;
  float rstd = rsqrtf(var + 1e-5f);
  u16* orow = out + (size_t)tok * D;
  orow[t]       = f2bf((v0 - mean) * rstd * w[t] + b[t]);
  orow[t + 256] = f2bf((v1 - mean) * rstd * w[t + 256] + b[t + 256]);
}

// ---------------------------------------------------------------------------
// Weight transpose+convert: src fp32 [K][N] -> dst bf16 [N][K]
__global__ __launch_bounds__(256) void transpose_cvt(
    const float* __restrict__ src, u16* __restrict__ dst,
    int K, int N, size_t sstride, size_t dstride) {
  __shared__ float tile[32][33];
  int n0 = blockIdx.x * 32, k0 = blockIdx.y * 32, l = blockIdx.z;
  src += (size_t)l * sstride;
  dst += (size_t)l * dstride;
  int tx = threadIdx.x & 31, ty = threadIdx.x >> 5;  // ty 0..7
  #pragma unroll
  for (int i = 0; i < 32; i += 8)
    tile[ty + i][tx] = src[(size_t)(k0 + ty + i) * N + n0 + tx];
  __syncthreads();
  #pragma unroll
  for (int i = 0; i < 32; i += 8)
    dst[(size_t)(n0 + ty + i) * K + k0 + tx] = f2bf(tile[tx][ty + i]);
}

__global__ __launch_bounds__(256) void concat_bias(
    const float* __restrict__ bq, const float* __restrict__ bk,
    const float* __restrict__ bv, float* __restrict__ dst) {
  int i = blockIdx.x * 256 + threadIdx.x;  // L*1536
  int l = i / 1536, c = i % 1536;
  float v = (c < 512) ? bq[l * 512 + c]
          : (c < 1024) ? bk[l * 512 + c - 512]
                       : bv[l * 512 + c - 1024];
  dst[i] = v;
}

// ---------------------------------------------------------------------------
// MFMA bf16 GEMM: C[M,N] = A[M,K] @ Bt[N,K]^T
// 128x128x32 tile, double-buffered LDS, counted-vmcnt pipeline (T4):
// raw s_barrier (NOT __syncthreads -> would emit vmcnt(0) drain), tile t+1
// stays in flight across the compute of tile t.
// XCD-chunked swizzle (T1) unchanged.
// EPI 0: QKV split -> q bf16, k bf16, v^T bf16 (N=1536)
// EPI 1: residual fp32: Cres += acc + bias
// EPI 2: gelu -> bf16 (Oq)
template <int EPI>
__global__ __launch_bounds__(256) void mfma_gemm(
    const u16* __restrict__ A, const u16* __restrict__ Bt,
    const float* __restrict__ bias, float* __restrict__ Cres,
    u16* __restrict__ Oq, u16* __restrict__ Ok, u16* __restrict__ Ovt,
    int M, int N, int K) {
  __shared__ u16 As[2][128 * 32];
  __shared__ u16 Bs[2][128 * 32];
  int t = threadIdx.x;
  int lane = t & 63, w = t >> 6;
  int wr = w >> 1, wc = w & 1;

  // ---- XCD-chunked bijective remap (gm % 8 == 0 guaranteed: gm = 96) ----
  int gm = gridDim.y, gn = gridDim.x;
  int wgid = blockIdx.y * gn + blockIdx.x;   // dispatch-linear id
  int xcd = wgid & 7;
  int c = wgid >> 3;
  int rpx = gm >> 3;                          // bm-rows per XCD
  int cg = c / gn;
  int bmi = xcd * rpx + cg;
  int bni = c - cg * gn;
  int bm = bmi * 128, bn = bni * 128;

  int l15 = lane & 15, l4 = lane >> 4;

  const u16* a0 = A + (size_t)(bm + (t >> 2)) * K + (t & 3) * 8;
  const u16* a1 = A + (size_t)(bm + 64 + (t >> 2)) * K + (t & 3) * 8;
  const u16* b0 = Bt + (size_t)(bn + (t >> 2)) * K + (t & 3) * 8;
  const u16* b1 = Bt + (size_t)(bn + 64 + (t >> 2)) * K + (t & 3) * 8;
  unsigned off0 = (unsigned)(t & 192) * 16u;          // wave-uniform byte base
  unsigned off1 = off0 + 256u * 16u;

  f32x4 acc[4][4];
  #pragma unroll
  for (int mi = 0; mi < 4; ++mi)
    #pragma unroll
    for (int nj = 0; nj < 4; ++nj)
      acc[mi][nj] = f32x4{0.f, 0.f, 0.f, 0.f};

  int nt = K >> 5;  // K-steps of 32 (>= 2 for all our shapes)

  // prologue: stage tiles 0 and 1 (8 loads in flight per wave)
  gld16(a0 + 0, (char*)As[0] + off0);
  gld16(a1 + 0, (char*)As[0] + off1);
  gld16(b0 + 0, (char*)Bs[0] + off0);
  gld16(b1 + 0, (char*)Bs[0] + off1);
  gld16(a0 + 32, (char*)As[1] + off0);
  gld16(a1 + 32, (char*)As[1] + off1);
  gld16(b0 + 32, (char*)Bs[1] + off0);
  gld16(b1 + 32, (char*)Bs[1] + off1);

  for (int tt = 0; tt < nt; ++tt) {
    // tile tt's 4 loads are the oldest outstanding; allow tile tt+1's 4 to fly
    if (tt < nt - 1) asm volatile("s_waitcnt vmcnt(4)" ::: "memory");
    else             asm volatile("s_waitcnt vmcnt(0)" ::: "memory");
    __builtin_amdgcn_s_barrier();          // all waves' tile-tt loads landed
    __builtin_amdgcn_sched_barrier(0);     // pin ds_reads below the barrier
    const u16* Asb = As[tt & 1];
    const u16* Bsb = Bs[tt & 1];
    bf16x8 af[4], bfr[4];
    #pragma unroll
    for (int mi = 0; mi < 4; ++mi)
      af[mi] = *(const bf16x8*)(Asb + (wr * 64 + mi * 16 + l15) * 32 + l4 * 8);
    #pragma unroll
    for (int nj = 0; nj < 4; ++nj)
      bfr[nj] = *(const bf16x8*)(Bsb + (wc * 64 + nj * 16 + l15) * 32 + l4 * 8);
    #pragma unroll
    for (int mi = 0; mi < 4; ++mi)
      #pragma unroll
      for (int nj = 0; nj < 4; ++nj)
        acc[mi][nj] = __builtin_amdgcn_mfma_f32_16x16x32_bf16(af[mi], bfr[nj], acc[mi][nj], 0, 0, 0);
    __builtin_amdgcn_sched_barrier(0);     // pin reads+MFMA above barrier
    __builtin_amdgcn_s_barrier();          // all waves done reading buf[tt&1]
    if (tt + 2 < nt) {
      int k0 = (tt + 2) * 32;
      char* Ad = (char*)As[tt & 1];
      char* Bd = (char*)Bs[tt & 1];
      gld16(a0 + k0, Ad + off0);
      gld16(a1 + k0, Ad + off1);
      gld16(b0 + k0, Bd + off0);
      gld16(b1 + k0, Bd + off1);
    }
  }

  int row00 = bm + wr * 64, col0 = bn + wc * 64;
  #pragma unroll
  for (int mi = 0; mi < 4; ++mi) {
    int rowb = row00 + mi * 16 + l4 * 4;
    #pragma unroll
    for (int nj = 0; nj < 4; ++nj) {
      int col = col0 + nj * 16 + l15;
      float bcol = bias[col];
      if (EPI == 0) {
        if (col < 512) {
          #pragma unroll
          for (int r = 0; r < 4; ++r)
            Oq[(size_t)(rowb + r) * D + col] = f2bf(acc[mi][nj][r] + bcol);
        } else if (col < 1024) {
          #pragma unroll
          for (int r = 0; r < 4; ++r)
            Ok[(size_t)(rowb + r) * D + (col - 512)] = f2bf(acc[mi][nj][r] + bcol);
        } else {
          int cv = col - 1024;
          int hh = cv >> 6, dk = cv & 63;
          int bb = rowb / S, ss = rowb - bb * S;
          u16x4 pk;
          #pragma unroll
          for (int r = 0; r < 4; ++r) pk[r] = f2bf(acc[mi][nj][r] + bcol);
          *(u16x4*)(Ovt + ((size_t)(bb * H + hh) * DK + dk) * S + ss) = pk;
        }
      } else if (EPI == 1) {
        #pragma unroll
        for (int r = 0; r < 4; ++r) {
          size_t ci = (size_t)(rowb + r) * N + col;
          Cres[ci] += acc[mi][nj][r] + bcol;
        }
      } else {  // GELU -> bf16
        #pragma unroll
        for (int r = 0; r < 4; ++r) {
          float v = acc[mi][nj][r] + bcol;
          v = 0.5f * v * (1.0f + erff(v * 0.70710678118654752f));
          Oq[(size_t)(rowb + r) * N + col] = f2bf(v);
        }
      }
    }
  }
}

// ---------------------------------------------------------------------------
// MFMA flash attention. Grid: (B*H, S/128). 4 waves x 32 queries.
__global__ __launch_bounds__(256) void attn_mfma(
    const u16* __restrict__ q, const u16* __restrict__ k,
    const u16* __restrict__ vt, const int* __restrict__ ids,
    u16* __restrict__ out) {
  __shared__ u16 Ks[64][72];
  __shared__ u16 Vs[64][72];   // V^T tile: [dk][key]
  __shared__ u16 Ps[4][32][72];
  __shared__ float Ms[64];
  int t = threadIdx.x, lane = t & 63, w = t >> 6;
  int l15 = lane & 15, l4 = lane >> 4;
  int bh = blockIdx.x;
  int b = bh >> 3, hh = bh & 7;
  int q0 = blockIdx.y * 128 + w * 32;

  // Preload Q fragments (2 m-frags x 2 k-steps)
  bf16x8 qf[2][2];
  const u16* qbase = q + (size_t)(b * S + q0) * D + hh * DK;
  #pragma unroll
  for (int mi = 0; mi < 2; ++mi)
    #pragma unroll
    for (int ks = 0; ks < 2; ++ks)
      qf[mi][ks] = *(const bf16x8*)(qbase + (size_t)(mi * 16 + l15) * D + ks * 32 + l4 * 8);

  float m[8], lsum[8];
  f32x4 accO[2][4];
  #pragma unroll
  for (int i = 0; i < 8; ++i) { m[i] = -3e38f; lsum[i] = 0.f; }
  #pragma unroll
  for (int mi = 0; mi < 2; ++mi)
    #pragma unroll
    for (int nj = 0; nj < 4; ++nj)
      accO[mi][nj] = f32x4{0.f, 0.f, 0.f, 0.f};

  for (int kb = 0; kb < S; kb += 64) {
    __syncthreads();
    #pragma unroll
    for (int i = 0; i < 2; ++i) {
      int slot = i * 256 + t;
      int rr = slot >> 3, ch = slot & 7;
      *(bf16x8*)(&Ks[rr][ch * 8]) =
          *(const bf16x8*)(k + (size_t)(b * S + kb + rr) * D + hh * DK + ch * 8);
      *(bf16x8*)(&Vs[rr][ch * 8]) =
          *(const bf16x8*)(vt + ((size_t)(b * H + hh) * DK + rr) * S + kb + ch * 8);
    }
    if (t < 64) Ms[t] = (ids[b * S + kb + t] == 0) ? -1e9f : 0.0f;
    __syncthreads();

    // QK^T
    f32x4 sc[2][4];
    #pragma unroll
    for (int mi = 0; mi < 2; ++mi)
      #pragma unroll
      for (int nj = 0; nj < 4; ++nj)
        sc[mi][nj] = f32x4{0.f, 0.f, 0.f, 0.f};
    #pragma unroll
    for (int ks = 0; ks < 2; ++ks) {
      bf16x8 kf[4];
      #pragma unroll
      for (int nj = 0; nj < 4; ++nj)
        kf[nj] = *(const bf16x8*)(&Ks[nj * 16 + l15][ks * 32 + l4 * 8]);
      #pragma unroll
      for (int mi = 0; mi < 2; ++mi)
        #pragma unroll
        for (int nj = 0; nj < 4; ++nj)
          sc[mi][nj] = __builtin_amdgcn_mfma_f32_16x16x32_bf16(qf[mi][ks], kf[nj], sc[mi][nj], 0, 0, 0);
    }
    // scale + mask
    #pragma unroll
    for (int mi = 0; mi < 2; ++mi)
      #pragma unroll
      for (int nj = 0; nj < 4; ++nj) {
        float mv = Ms[nj * 16 + l15];
        #pragma unroll
        for (int r = 0; r < 4; ++r)
          sc[mi][nj][r] = sc[mi][nj][r] * 0.125f + mv;
      }
    // online softmax (rows live in lanes with same l4)
    #pragma unroll
    for (int mi = 0; mi < 2; ++mi)
      #pragma unroll
      for (int r = 0; r < 4; ++r) {
        int ridx = mi * 4 + r;
        float mx = sc[mi][0][r];
        #pragma unroll
        for (int nj = 1; nj < 4; ++nj) mx = fmaxf(mx, sc[mi][nj][r]);
        #pragma unroll
        for (int o = 1; o < 16; o <<= 1) mx = fmaxf(mx, __shfl_xor(mx, o));
        float mnew = fmaxf(m[ridx], mx);
        float scale = __expf(m[ridx] - mnew);
        float rs = 0.f;
        #pragma unroll
        for (int nj = 0; nj < 4; ++nj) {
          float p = __expf(sc[mi][nj][r] - mnew);
          sc[mi][nj][r] = p;
          rs += p;
        }
        #pragma unroll
        for (int o = 1; o < 16; o <<= 1) rs += __shfl_xor(rs, o);
        lsum[ridx] = lsum[ridx] * scale + rs;
        m[ridx] = mnew;
        #pragma unroll
        for (int nj = 0; nj < 4; ++nj) accO[mi][nj][r] *= scale;
      }
    // P -> bf16 -> wave-private LDS
    #pragma unroll
    for (int mi = 0; mi < 2; ++mi)
      #pragma unroll
      for (int nj = 0; nj < 4; ++nj)
        #pragma unroll
        for (int r = 0; r < 4; ++r)
          Ps[w][mi * 16 + l4 * 4 + r][nj * 16 + l15] = f2bf(sc[mi][nj][r]);
    // PV
    #pragma unroll
    for (int ks2 = 0; ks2 < 2; ++ks2) {
      bf16x8 pf[2], vf[4];
      #pragma unroll
      for (int mi = 0; mi < 2; ++mi)
        pf[mi] = *(const bf16x8*)(&Ps[w][mi * 16 + l15][ks2 * 32 + l4 * 8]);
      #pragma unroll
      for (int nj = 0; nj < 4; ++nj)
        vf[nj] = *(const bf16x8*)(&Vs[nj * 16 + l15][ks2 * 32 + l4 * 8]);
      #pragma unroll
      for (int mi = 0; mi < 2; ++mi)
        #pragma unroll
        for (int nj = 0; nj < 4; ++nj)
          accO[mi][nj] = __builtin_amdgcn_mfma_f32_16x16x32_bf16(pf[mi], vf[nj], accO[mi][nj], 0, 0, 0);
    }
  }

  // output bf16 [TOK][D]
  #pragma unroll
  for (int mi = 0; mi < 2; ++mi)
    #pragma unroll
    for (int nj = 0; nj < 4; ++nj)
      #pragma unroll
      for (int r = 0; r < 4; ++r) {
        int row = b * S + q0 + mi * 16 + l4 * 4 + r;
        out[(size_t)row * D + hh * DK + nj * 16 + l15] =
            f2bf(accO[mi][nj][r] / lsum[mi * 4 + r]);
      }
}

// ---------------------------------------------------------------------------
__global__ __launch_bounds__(512) void pool_kernel(
    const float* __restrict__ x, const float* __restrict__ inten,
    float* __restrict__ out) {
  int b = blockIdx.x;
  int d = threadIdx.x;
  float acc = 0.f;
  for (int s = 0; s < S; ++s)
    acc += inten[b * S + s] * x[((size_t)b * S + s) * D + d];
  out[b * D + d] = acc;
}

// ---------------------------------------------------------------------------
extern "C" void kernel_launch(void* const* d_in, const int* in_sizes, int n_in,
                              void* d_out, int out_size, void* d_ws, size_t ws_size,
                              hipStream_t stream) {
  const int* input_id    = (const int*)d_in[0];
  const float* intensity = (const float*)d_in[1];
  const float* emb = (const float*)d_in[2];
  const float* iw  = (const float*)d_in[3];
  const float* ib  = (const float*)d_in[4];
  const float* Wq  = (const float*)d_in[5];
  const float* bq  = (const float*)d_in[6];
  const float* Wk  = (const float*)d_in[7];
  const float* bk  = (const float*)d_in[8];
  const float* Wv  = (const float*)d_in[9];
  const float* bv  = (const float*)d_in[10];
  const float* Wo  = (const float*)d_in[11];
  const float* bo  = (const float*)d_in[12];
  const float* ln1w = (const float*)d_in[13];
  const float* ln1b = (const float*)d_in[14];
  const float* ln2w = (const float*)d_in[15];
  const float* ln2b = (const float*)d_in[16];
  const float* W1  = (const float*)d_in[17];
  const float* b1  = (const float*)d_in[18];
  const float* W2  = (const float*)d_in[19];
  const float* b2  = (const float*)d_in[20];
  float* outp = (float*)d_out;

  float *x, *bqkv;
  u16 *h, *q, *k, *vt, *ffn, *qkvT, *woT, *w1T, *w2T;
  { void* p; hipGetSymbolAddress(&p, HIP_SYMBOL(g_x));    x    = (float*)p; }
  { void* p; hipGetSymbolAddress(&p, HIP_SYMBOL(g_h));    h    = (u16*)p; }
  { void* p; hipGetSymbolAddress(&p, HIP_SYMBOL(g_q));    q    = (u16*)p; }
  { void* p; hipGetSymbolAddress(&p, HIP_SYMBOL(g_k));    k    = (u16*)p; }
  { void* p; hipGetSymbolAddress(&p, HIP_SYMBOL(g_vt));   vt   = (u16*)p; }
  { void* p; hipGetSymbolAddress(&p, HIP_SYMBOL(g_ffn));  ffn  = (u16*)p; }
  { void* p; hipGetSymbolAddress(&p, HIP_SYMBOL(g_qkvT)); qkvT = (u16*)p; }
  { void* p; hipGetSymbolAddress(&p, HIP_SYMBOL(g_woT));  woT  = (u16*)p; }
  { void* p; hipGetSymbolAddress(&p, HIP_SYMBOL(g_w1T));  w1T  = (u16*)p; }
  { void* p; hipGetSymbolAddress(&p, HIP_SYMBOL(g_w2T));  w2T  = (u16*)p; }
  { void* p; hipGetSymbolAddress(&p, HIP_SYMBOL(g_bqkv)); bqkv = (float*)p; }

  // ---- weight prep (per launch; deterministic) ----
  dim3 t256(256);
  transpose_cvt<<<dim3(16, 16, L), t256, 0, stream>>>(Wq, qkvT + 0 * D * D, D, D, (size_t)D * D, (size_t)3 * D * D);
  transpose_cvt<<<dim3(16, 16, L), t256, 0, stream>>>(Wk, qkvT + 1 * D * D, D, D, (size_t)D * D, (size_t)3 * D * D);
  transpose_cvt<<<dim3(16, 16, L), t256, 0, stream>>>(Wv, qkvT + 2 * D * D, D, D, (size_t)D * D, (size_t)3 * D * D);
  transpose_cvt<<<dim3(16, 16, L), t256, 0, stream>>>(Wo, woT, D, D, (size_t)D * D, (size_t)D * D);
  transpose_cvt<<<dim3(64, 16, L), t256, 0, stream>>>(W1, w1T, D, DFF, (size_t)D * DFF, (size_t)D * DFF);
  transpose_cvt<<<dim3(16, 64, L), t256, 0, stream>>>(W2, w2T, DFF, D, (size_t)DFF * D, (size_t)DFF * D);
  concat_bias<<<L * 3 * D / 256, t256, 0, stream>>>(bq, bk, bv, bqkv);

  embed_kernel<<<TOK, t256, 0, stream>>>(input_id, intensity, emb, iw, ib, x);

  for (int l = 0; l < L; ++l) {
    const u16* qkvT_l = qkvT + (size_t)l * 3 * D * D;
    const u16* woT_l  = woT + (size_t)l * D * D;
    const u16* w1T_l  = w1T + (size_t)l * D * DFF;
    const u16* w2T_l  = w2T + (size_t)l * DFF * D;

    ln_kernel<<<TOK, t256, 0, stream>>>(x, ln1w + (size_t)l * D, ln1b + (size_t)l * D, h);
    mfma_gemm<0><<<dim3(12, 96), t256, 0, stream>>>(h, qkvT_l, bqkv + l * 3 * D,
                                                    nullptr, q, k, vt, TOK, 3 * D, D);
    attn_mfma<<<dim3(B * H, S / 128), t256, 0, stream>>>(q, k, vt, input_id, h);
    mfma_gemm<1><<<dim3(4, 96), t256, 0, stream>>>(h, woT_l, bo + (size_t)l * D,
                                                   x, nullptr, nullptr, nullptr, TOK, D, D);
    ln_kernel<<<TOK, t256, 0, stream>>>(x, ln2w + (size_t)l * D, ln2b + (size_t)l * D, h);
    mfma_gemm<2><<<dim3(16, 96), t256, 0, stream>>>(h, w1T_l, b1 + (size_t)l * DFF,
                                                    nullptr, ffn, nullptr, nullptr, TOK, DFF, D);
    mfma_gemm<1><<<dim3(4, 96), t256, 0, stream>>>(ffn, w2T_l, b2 + (size_t)l * D,
                                                   x, nullptr, nullptr, nullptr, TOK, D, DFF);
  }

  pool_kernel<<<B, 512, 0, stream>>>(x, intensity, outp);
}